// Round 6
// baseline (306.301 us; speedup 1.0000x reference)
//
#include <hip/hip_runtime.h>

// TrueEpisodicMemory round 6: conflict-free XOR-swizzled LDS (all tiles), 512-thread
// blocks (8 waves, 16 rows each, 2 blocks/CU = 50% occ), depth-3 counted-vmcnt pipeline.
// out[b,:] = softmax_m(q[b]·mk[m] + 0.5*cx[b]·mc[m] + exp(0.1*ts[m])) · mv
// B=131072, M=100 (pad 112/128), D=1024, C=16.
// Bank math: every b128 phase (16 lanes) hits all 8 bank-quads exactly twice (free).
//   Q [row][slot^(row&7)], K [m][slot^((m>>1)&3)], V [d][slot^(d&15)], P [r][slot^r].
// global_load_lds dests stay linear; the swizzle is applied to the GLOBAL source (rule #21).

typedef __attribute__((ext_vector_type(8))) _Float16 f16x8;
typedef __attribute__((ext_vector_type(4))) float f32x4;

constexpr int DQ = 1024, CD = 16, MM = 100, KD = 1056, NT = 7;
constexpr size_t KE = (size_t)112 * KD;

// LDS (bytes): QK phase: Q[3][128][8 slot][16] @0 (16 KB ea), K[3][112][4 slot][16] @49152.
// PV phase overlay: P[8 wave][16][128]f16 @0 (32 KB), V[3][32][16 slot][16] @32768 (8 KB ea).
constexpr int QBUF = 16384, KOFF = 49152, KBUF = 7168;
constexpr int VOFF = 32768, VBUF = 8192;
constexpr int LDSZ = 70656;

#define WAITV(n) asm volatile("s_waitcnt vmcnt(" #n ")" ::: "memory")

__device__ __forceinline__ void gl16(const void* g, void* l) {
    __builtin_amdgcn_global_load_lds(
        (const __attribute__((address_space(1))) unsigned int*)g,
        (__attribute__((address_space(3))) unsigned int*)l, 16, 0, 0);
}

// ---------------- prologue: fp16 K [112][1056], ctx folded at cols 1024..1039 ----------------
__global__ void build_k(const float* __restrict__ mk, const float* __restrict__ mc,
                        _Float16* __restrict__ KH)
{
    int d = blockIdx.x * 64 + threadIdx.x;
    int m = blockIdx.y;
    if (d >= KD) return;
    float x = 0.f;
    if (m < MM) {
        if (d < DQ)            x = mk[(size_t)m * DQ + d];
        else if (d < DQ + CD)  x = 0.5f * mc[(size_t)m * CD + (d - DQ)];
    }
    KH[(size_t)m * KD + d] = (_Float16)x;
}

// ---------------- prologue: fp16 V^T [1024][128] (cols 100..127 zero) ----------------
__global__ void build_vt(const float* __restrict__ mv, _Float16* __restrict__ VT)
{
    int idx = blockIdx.x * 256 + threadIdx.x;   // 0..131071
    int d = idx >> 7, m = idx & 127;
    VT[idx] = (m < MM) ? (_Float16)mv[(size_t)m * DQ + d] : (_Float16)0.f;
}

// ---------------- main fused kernel: 512 threads, 128 rows/block ----------------
__global__ __launch_bounds__(512, 4)
void epmem_pipe(const float* __restrict__ q, const float* __restrict__ cx,
                const float* __restrict__ ts,
                const _Float16* __restrict__ KH, const _Float16* __restrict__ VT,
                float* __restrict__ out)
{
    __shared__ __align__(16) char lds[LDSZ];

    const int t = threadIdx.x, w = t >> 6, lane = t & 63;
    const int lr = lane & 15, lk = lane >> 4;
    const int row0 = blockIdx.x * 128;

    // time-decay bias first: these vmem loads are oldest -> drained by the first WAITV
    float dec[NT];
    #pragma unroll
    for (int nt = 0; nt < NT; ++nt) {
        int m = nt * 16 + lr;
        dec[nt] = (m < MM) ? __expf(0.1f * ts[m]) : 0.f;
    }

    // ---- staging (linear LDS dest = wave-uniform base + lane*16; swizzle on global src) ----
    auto stageQ = [&](int buf, int ks) {            // 1024 segs, 2/thread
        char* dst = lds + buf * QBUF;
        #pragma unroll
        for (int i = 0; i < 2; ++i) {
            int s = i * 512 + w * 64 + lane;        // seg: row s>>3, phys slot s&7
            int row = s >> 3;
            int logical = (s & 7) ^ (row & 7);
            gl16(q + (size_t)(row0 + row) * DQ + ks * 32 + logical * 4,
                 dst + (i * 512 + w * 64) * 16);
        }
    };
    auto stageQctx = [&](int buf) {                 // [128][4 slot] packed, 512 segs, 1/thread
        char* dst = lds + buf * QBUF;
        gl16(cx + (size_t)(row0 + (t >> 2)) * CD + (t & 3) * 4, dst + (w * 64) * 16);
    };
    auto stageK = [&](int buf, int ks) {            // 448 segs, 1/thread for w<7
        if (w < 7) {
            char* dst = lds + KOFF + buf * KBUF;
            int s = w * 64 + lane;                  // seg: m s>>2, phys slot s&3
            int m = s >> 2;
            int logical = (s & 3) ^ ((m >> 1) & 3);
            gl16(KH + (size_t)m * KD + ks * 32 + logical * 8, dst + (w * 64) * 16);
        }
    };
    auto stageV = [&](int buf, int c) {             // 512 segs, 1/thread
        char* dst = lds + VOFF + buf * VBUF;
        int d = t >> 4;                             // 0..31
        int logical = (t & 15) ^ (d & 15);
        gl16(VT + (size_t)(c * 32 + d) * 128 + logical * 8, dst + (w * 64) * 16);
    };

    f32x4 acc[NT];
    #pragma unroll
    for (int nt = 0; nt < NT; ++nt) acc[nt] = (f32x4){0.f, 0.f, 0.f, 0.f};

    // ---------- QK^T: 33 chunk-steps (chunk 32 = ctx), depth-3, counted vmcnt ----------
    stageQ(0, 0); stageK(0, 0);
    stageQ(1, 1); stageK(1, 1);
    if (w < 7) { WAITV(3); } else { WAITV(2); }     // chunk 0 resident; chunk 1 in flight
    __builtin_amdgcn_s_barrier();

    int bc = 0;
    for (int ks = 0; ks <= 32; ++ks) {
        int bs = bc + 2; if (bs >= 3) bs -= 3;
        if (ks + 2 < 32)       { stageQ(bs, ks + 2); stageK(bs, ks + 2); }
        else if (ks + 2 == 32) { stageQctx(bs);      stageK(bs, 32); }

        const char* qb = lds + bc * QBUF;
        f16x8 ah, al;
        if (ks < 32) {
            const char* base = qb + (w * 16 + lr) * 128;
            const int g = lr & 7;
            f32x4 x = *(const f32x4*)(base + (((2 * lk)     ^ g) << 4));
            f32x4 y = *(const f32x4*)(base + (((2 * lk + 1) ^ g) << 4));
            #pragma unroll
            for (int e = 0; e < 4; ++e) {
                _Float16 h = (_Float16)x[e]; ah[e] = h;     al[e] = (_Float16)(x[e] - (float)h);
                h = (_Float16)y[e];          ah[4 + e] = h; al[4 + e] = (_Float16)(y[e] - (float)h);
            }
        } else {
            if (lk < 2) {
                const char* base = qb + (w * 16 + lr) * 64;
                f32x4 x = *(const f32x4*)(base + (2 * lk) * 16);
                f32x4 y = *(const f32x4*)(base + (2 * lk + 1) * 16);
                #pragma unroll
                for (int e = 0; e < 4; ++e) {
                    _Float16 h = (_Float16)x[e]; ah[e] = h;     al[e] = (_Float16)(x[e] - (float)h);
                    h = (_Float16)y[e];          ah[4 + e] = h; al[4 + e] = (_Float16)(y[e] - (float)h);
                }
            } else {
                #pragma unroll
                for (int e = 0; e < 8; ++e) { ah[e] = (_Float16)0.f; al[e] = (_Float16)0.f; }
            }
        }
        #pragma unroll
        for (int nt = 0; nt < NT; ++nt) {
            int m = nt * 16 + lr;
            f16x8 bh = *(const f16x8*)(lds + KOFF + bc * KBUF
                         + ((m << 2) + (lk ^ ((lr >> 1) & 3))) * 16);
            acc[nt] = __builtin_amdgcn_mfma_f32_16x16x32_f16(ah, bh, acc[nt], 0, 0, 0);
            acc[nt] = __builtin_amdgcn_mfma_f32_16x16x32_f16(al, bh, acc[nt], 0, 0, 0);
        }
        // counted waits: chunk ks+1 resident before next step; never drain mid-loop
        if (ks <= 29)      { if (w < 7) { WAITV(3); } else { WAITV(2); } }
        else if (ks == 30) { if (w < 7) { WAITV(2); } else { WAITV(1); } }
        else if (ks == 31) { WAITV(0); }
        if (ks < 32) __builtin_amdgcn_s_barrier();
        if (++bc == 3) bc = 0;
    }

    __builtin_amdgcn_s_barrier();               // all QK LDS reads done; V/P may overlay
    stageV(0, 0); stageV(1, 1);                 // V latency hides under softmax

    // ---------- softmax, fully in-register (wave owns rows w*16..w*16+15) ----------
    char* Pb = lds + w * 4096;                  // wave-private P [16][128]f16, slot-swizzled
    {
        float rm[4] = {-3e38f, -3e38f, -3e38f, -3e38f};
        #pragma unroll
        for (int nt = 0; nt < NT; ++nt) {
            int m = nt * 16 + lr;
            #pragma unroll
            for (int r = 0; r < 4; ++r) {
                float s = (m < MM) ? (acc[nt][r] + dec[nt]) : -3e38f;
                acc[nt][r] = s;
                rm[r] = fmaxf(rm[r], s);
            }
        }
        #pragma unroll
        for (int r = 0; r < 4; ++r)
            #pragma unroll
            for (int off = 1; off < 16; off <<= 1)
                rm[r] = fmaxf(rm[r], __shfl_xor(rm[r], off));
        float rs[4] = {0.f, 0.f, 0.f, 0.f};
        #pragma unroll
        for (int nt = 0; nt < NT; ++nt)
            #pragma unroll
            for (int r = 0; r < 4; ++r) {
                float e = __expf(acc[nt][r] - rm[r]);
                acc[nt][r] = e;
                rs[r] += e;
            }
        #pragma unroll
        for (int r = 0; r < 4; ++r)
            #pragma unroll
            for (int off = 1; off < 16; off <<= 1)
                rs[r] += __shfl_xor(rs[r], off);
        #pragma unroll
        for (int r = 0; r < 4; ++r) {
            float inv = 1.f / rs[r];
            int row = 4 * lk + r;
            #pragma unroll
            for (int nt = 0; nt < NT; ++nt)
                *(_Float16*)(Pb + row * 256 + (((nt * 2 + (lr >> 3)) ^ row) & 15) * 16
                             + (lr & 7) * 2) = (_Float16)(acc[nt][r] * inv);
        }
    }
    if (lane < 32) {                            // zero-pad P cols 112..127 (slots 14,15)
        int row = lane >> 1, sl = 14 + (lane & 1);
        uint4 z = {0u, 0u, 0u, 0u};
        *(uint4*)(Pb + row * 256 + ((sl ^ row) & 15) * 16) = z;
    }
    WAITV(1);                                   // V chunk 0 resident; chunk 1 in flight
    __builtin_amdgcn_s_barrier();

    // ---------- PV: 32 d-chunk steps, depth-3, counted vmcnt (8 stores + loads) ----------
    f16x8 pa[4];
    #pragma unroll
    for (int k4 = 0; k4 < 4; ++k4)
        pa[k4] = *(const f16x8*)(Pb + lr * 256 + (((k4 * 4 + lk) ^ lr) & 15) * 16);

    int vc = 0;
    for (int c = 0; c < 32; ++c) {
        int vs = vc + 2; if (vs >= 3) vs -= 3;
        if (c + 2 < 32) stageV(vs, c + 2);
        f32x4 o0 = {0.f, 0.f, 0.f, 0.f}, o1 = {0.f, 0.f, 0.f, 0.f};
        #pragma unroll
        for (int k4 = 0; k4 < 4; ++k4) {
            const char* vb = lds + VOFF + vc * VBUF + (((k4 * 4 + lk) ^ lr) & 15) * 16;
            f16x8 b0 = *(const f16x8*)(vb + lr * 256);          // d = lr
            f16x8 b1 = *(const f16x8*)(vb + (16 + lr) * 256);   // d = 16+lr (same swizzle: d&15=lr)
            o0 = __builtin_amdgcn_mfma_f32_16x16x32_f16(pa[k4], b0, o0, 0, 0, 0);
            o1 = __builtin_amdgcn_mfma_f32_16x16x32_f16(pa[k4], b1, o1, 0, 0, 0);
        }
        #pragma unroll
        for (int r = 0; r < 4; ++r) {
            size_t rw = (size_t)(row0 + w * 16 + 4 * lk + r) * DQ + c * 32;
            out[rw + lr]      = o0[r];
            out[rw + 16 + lr] = o1[r];
        }
        if (c == 0)       { WAITV(9); }         // V(1) done: newer = V(2)+8 stores
        else if (c <= 29) { WAITV(17); }        // V(c+1) done: newer = 8+1+8
        else if (c == 30) { WAITV(16); }        // no V(32) stage: newer = 8+8
        if (c < 31) __builtin_amdgcn_s_barrier();
        if (++vc == 3) vc = 0;
    }
}

extern "C" void kernel_launch(void* const* d_in, const int* in_sizes, int n_in,
                              void* d_out, int out_size, void* d_ws, size_t ws_size,
                              hipStream_t stream) {
    const float* q  = (const float*)d_in[0];
    const float* cx = (const float*)d_in[1];
    const float* mk = (const float*)d_in[2];
    const float* mv = (const float*)d_in[3];
    const float* mc = (const float*)d_in[4];
    const float* ts = (const float*)d_in[5];
    float* out = (float*)d_out;

    _Float16* wsp = (_Float16*)d_ws;
    _Float16* KH = wsp;                        // [112][1056]
    _Float16* VT = wsp + KE;                   // [1024][128]

    const int B = in_sizes[0] / DQ;            // 131072

    build_k<<<dim3(17, 112), dim3(64), 0, stream>>>(mk, mc, KH);
    build_vt<<<dim3(512), dim3(256), 0, stream>>>(mv, VT);
    epmem_pipe<<<dim3(B / 128), dim3(512), 0, stream>>>(q, cx, ts, KH, VT, out);
}

// Round 11
// 296.253 us; speedup vs baseline: 1.0339x; 1.0339x over previous
//
#include <hip/hip_runtime.h>

// TrueEpisodicMemory round 11: EXACT round-6 kernel (HW-passed, 306us) with ONE change:
// out stores use __builtin_nontemporal_store (L2 write-around), so the 533-MB out stream
// stops evicting the K/V staging hot set from the per-XCD L2s. Everything else verbatim.
// out[b,:] = softmax_m(q[b]·mk[m] + 0.5*cx[b]·mc[m] + exp(0.1*ts[m])) · mv
// B=131072, M=100 (pad 112/128), D=1024, C=16.

typedef __attribute__((ext_vector_type(8))) _Float16 f16x8;
typedef __attribute__((ext_vector_type(4))) float f32x4;

constexpr int DQ = 1024, CD = 16, MM = 100, KD = 1056, NT = 7;
constexpr size_t KE = (size_t)112 * KD;

// LDS (bytes): QK phase: Q[3][128][8 slot][16] @0 (16 KB ea), K[3][112][4 slot][16] @49152.
// PV phase overlay: P[8 wave][16][128]f16 @0 (32 KB), V[3][32][16 slot][16] @32768 (8 KB ea).
constexpr int QBUF = 16384, KOFF = 49152, KBUF = 7168;
constexpr int VOFF = 32768, VBUF = 8192;
constexpr int LDSZ = 70656;

#define WAITV(n) asm volatile("s_waitcnt vmcnt(" #n ")" ::: "memory")

__device__ __forceinline__ void gl16(const void* g, void* l) {
    __builtin_amdgcn_global_load_lds(
        (const __attribute__((address_space(1))) unsigned int*)g,
        (__attribute__((address_space(3))) unsigned int*)l, 16, 0, 0);
}

// ---------------- prologue: fp16 K [112][1056], ctx folded at cols 1024..1039 ----------------
__global__ void build_k(const float* __restrict__ mk, const float* __restrict__ mc,
                        _Float16* __restrict__ KH)
{
    int d = blockIdx.x * 64 + threadIdx.x;
    int m = blockIdx.y;
    if (d >= KD) return;
    float x = 0.f;
    if (m < MM) {
        if (d < DQ)            x = mk[(size_t)m * DQ + d];
        else if (d < DQ + CD)  x = 0.5f * mc[(size_t)m * CD + (d - DQ)];
    }
    KH[(size_t)m * KD + d] = (_Float16)x;
}

// ---------------- prologue: fp16 V^T [1024][128] (cols 100..127 zero) ----------------
__global__ void build_vt(const float* __restrict__ mv, _Float16* __restrict__ VT)
{
    int idx = blockIdx.x * 256 + threadIdx.x;   // 0..131071
    int d = idx >> 7, m = idx & 127;
    VT[idx] = (m < MM) ? (_Float16)mv[(size_t)m * DQ + d] : (_Float16)0.f;
}

// ---------------- main fused kernel: 512 threads, 128 rows/block ----------------
__global__ __launch_bounds__(512, 4)
void epmem_pipe(const float* __restrict__ q, const float* __restrict__ cx,
                const float* __restrict__ ts,
                const _Float16* __restrict__ KH, const _Float16* __restrict__ VT,
                float* __restrict__ out)
{
    __shared__ __align__(16) char lds[LDSZ];

    const int t = threadIdx.x, w = t >> 6, lane = t & 63;
    const int lr = lane & 15, lk = lane >> 4;
    const int row0 = blockIdx.x * 128;

    // time-decay bias first: these vmem loads are oldest -> drained by the first WAITV
    float dec[NT];
    #pragma unroll
    for (int nt = 0; nt < NT; ++nt) {
        int m = nt * 16 + lr;
        dec[nt] = (m < MM) ? __expf(0.1f * ts[m]) : 0.f;
    }

    // ---- staging (linear LDS dest = wave-uniform base + lane*16; swizzle on global src) ----
    auto stageQ = [&](int buf, int ks) {            // 1024 segs, 2/thread
        char* dst = lds + buf * QBUF;
        #pragma unroll
        for (int i = 0; i < 2; ++i) {
            int s = i * 512 + w * 64 + lane;        // seg: row s>>3, phys slot s&7
            int row = s >> 3;
            int logical = (s & 7) ^ (row & 7);
            gl16(q + (size_t)(row0 + row) * DQ + ks * 32 + logical * 4,
                 dst + (i * 512 + w * 64) * 16);
        }
    };
    auto stageQctx = [&](int buf) {                 // [128][4 slot] packed, 512 segs, 1/thread
        char* dst = lds + buf * QBUF;
        gl16(cx + (size_t)(row0 + (t >> 2)) * CD + (t & 3) * 4, dst + (w * 64) * 16);
    };
    auto stageK = [&](int buf, int ks) {            // 448 segs, 1/thread for w<7
        if (w < 7) {
            char* dst = lds + KOFF + buf * KBUF;
            int s = w * 64 + lane;                  // seg: m s>>2, phys slot s&3
            int m = s >> 2;
            int logical = (s & 3) ^ ((m >> 1) & 3);
            gl16(KH + (size_t)m * KD + ks * 32 + logical * 8, dst + (w * 64) * 16);
        }
    };
    auto stageV = [&](int buf, int c) {             // 512 segs, 1/thread
        char* dst = lds + VOFF + buf * VBUF;
        int d = t >> 4;                             // 0..31
        int logical = (t & 15) ^ (d & 15);
        gl16(VT + (size_t)(c * 32 + d) * 128 + logical * 8, dst + (w * 64) * 16);
    };

    f32x4 acc[NT];
    #pragma unroll
    for (int nt = 0; nt < NT; ++nt) acc[nt] = (f32x4){0.f, 0.f, 0.f, 0.f};

    // ---------- QK^T: 33 chunk-steps (chunk 32 = ctx), depth-3, counted vmcnt ----------
    stageQ(0, 0); stageK(0, 0);
    stageQ(1, 1); stageK(1, 1);
    if (w < 7) { WAITV(3); } else { WAITV(2); }     // chunk 0 resident; chunk 1 in flight
    __builtin_amdgcn_s_barrier();

    int bc = 0;
    for (int ks = 0; ks <= 32; ++ks) {
        int bs = bc + 2; if (bs >= 3) bs -= 3;
        if (ks + 2 < 32)       { stageQ(bs, ks + 2); stageK(bs, ks + 2); }
        else if (ks + 2 == 32) { stageQctx(bs);      stageK(bs, 32); }

        const char* qb = lds + bc * QBUF;
        f16x8 ah, al;
        if (ks < 32) {
            const char* base = qb + (w * 16 + lr) * 128;
            const int g = lr & 7;
            f32x4 x = *(const f32x4*)(base + (((2 * lk)     ^ g) << 4));
            f32x4 y = *(const f32x4*)(base + (((2 * lk + 1) ^ g) << 4));
            #pragma unroll
            for (int e = 0; e < 4; ++e) {
                _Float16 h = (_Float16)x[e]; ah[e] = h;     al[e] = (_Float16)(x[e] - (float)h);
                h = (_Float16)y[e];          ah[4 + e] = h; al[4 + e] = (_Float16)(y[e] - (float)h);
            }
        } else {
            if (lk < 2) {
                const char* base = qb + (w * 16 + lr) * 64;
                f32x4 x = *(const f32x4*)(base + (2 * lk) * 16);
                f32x4 y = *(const f32x4*)(base + (2 * lk + 1) * 16);
                #pragma unroll
                for (int e = 0; e < 4; ++e) {
                    _Float16 h = (_Float16)x[e]; ah[e] = h;     al[e] = (_Float16)(x[e] - (float)h);
                    h = (_Float16)y[e];          ah[4 + e] = h; al[4 + e] = (_Float16)(y[e] - (float)h);
                }
            } else {
                #pragma unroll
                for (int e = 0; e < 8; ++e) { ah[e] = (_Float16)0.f; al[e] = (_Float16)0.f; }
            }
        }
        #pragma unroll
        for (int nt = 0; nt < NT; ++nt) {
            int m = nt * 16 + lr;
            f16x8 bh = *(const f16x8*)(lds + KOFF + bc * KBUF
                         + ((m << 2) + (lk ^ ((lr >> 1) & 3))) * 16);
            acc[nt] = __builtin_amdgcn_mfma_f32_16x16x32_f16(ah, bh, acc[nt], 0, 0, 0);
            acc[nt] = __builtin_amdgcn_mfma_f32_16x16x32_f16(al, bh, acc[nt], 0, 0, 0);
        }
        // counted waits: chunk ks+1 resident before next step; never drain mid-loop
        if (ks <= 29)      { if (w < 7) { WAITV(3); } else { WAITV(2); } }
        else if (ks == 30) { if (w < 7) { WAITV(2); } else { WAITV(1); } }
        else if (ks == 31) { WAITV(0); }
        if (ks < 32) __builtin_amdgcn_s_barrier();
        if (++bc == 3) bc = 0;
    }

    __builtin_amdgcn_s_barrier();               // all QK LDS reads done; V/P may overlay
    stageV(0, 0); stageV(1, 1);                 // V latency hides under softmax

    // ---------- softmax, fully in-register (wave owns rows w*16..w*16+15) ----------
    char* Pb = lds + w * 4096;                  // wave-private P [16][128]f16, slot-swizzled
    {
        float rm[4] = {-3e38f, -3e38f, -3e38f, -3e38f};
        #pragma unroll
        for (int nt = 0; nt < NT; ++nt) {
            int m = nt * 16 + lr;
            #pragma unroll
            for (int r = 0; r < 4; ++r) {
                float s = (m < MM) ? (acc[nt][r] + dec[nt]) : -3e38f;
                acc[nt][r] = s;
                rm[r] = fmaxf(rm[r], s);
            }
        }
        #pragma unroll
        for (int r = 0; r < 4; ++r)
            #pragma unroll
            for (int off = 1; off < 16; off <<= 1)
                rm[r] = fmaxf(rm[r], __shfl_xor(rm[r], off));
        float rs[4] = {0.f, 0.f, 0.f, 0.f};
        #pragma unroll
        for (int nt = 0; nt < NT; ++nt)
            #pragma unroll
            for (int r = 0; r < 4; ++r) {
                float e = __expf(acc[nt][r] - rm[r]);
                acc[nt][r] = e;
                rs[r] += e;
            }
        #pragma unroll
        for (int r = 0; r < 4; ++r)
            #pragma unroll
            for (int off = 1; off < 16; off <<= 1)
                rs[r] += __shfl_xor(rs[r], off);
        #pragma unroll
        for (int r = 0; r < 4; ++r) {
            float inv = 1.f / rs[r];
            int row = 4 * lk + r;
            #pragma unroll
            for (int nt = 0; nt < NT; ++nt)
                *(_Float16*)(Pb + row * 256 + (((nt * 2 + (lr >> 3)) ^ row) & 15) * 16
                             + (lr & 7) * 2) = (_Float16)(acc[nt][r] * inv);
        }
    }
    if (lane < 32) {                            // zero-pad P cols 112..127 (slots 14,15)
        int row = lane >> 1, sl = 14 + (lane & 1);
        uint4 z = {0u, 0u, 0u, 0u};
        *(uint4*)(Pb + row * 256 + ((sl ^ row) & 15) * 16) = z;
    }
    WAITV(1);                                   // V chunk 0 resident; chunk 1 in flight
    __builtin_amdgcn_s_barrier();

    // ---------- PV: 32 d-chunk steps, depth-3, counted vmcnt (8 stores/step) ----------
    f16x8 pa[4];
    #pragma unroll
    for (int k4 = 0; k4 < 4; ++k4)
        pa[k4] = *(const f16x8*)(Pb + lr * 256 + (((k4 * 4 + lk) ^ lr) & 15) * 16);

    int vc = 0;
    for (int c = 0; c < 32; ++c) {
        int vs = vc + 2; if (vs >= 3) vs -= 3;
        if (c + 2 < 32) stageV(vs, c + 2);
        f32x4 o0 = {0.f, 0.f, 0.f, 0.f}, o1 = {0.f, 0.f, 0.f, 0.f};
        #pragma unroll
        for (int k4 = 0; k4 < 4; ++k4) {
            const char* vb = lds + VOFF + vc * VBUF + (((k4 * 4 + lk) ^ lr) & 15) * 16;
            f16x8 b0 = *(const f16x8*)(vb + lr * 256);          // d = lr
            f16x8 b1 = *(const f16x8*)(vb + (16 + lr) * 256);   // d = 16+lr (same swizzle: d&15=lr)
            o0 = __builtin_amdgcn_mfma_f32_16x16x32_f16(pa[k4], b0, o0, 0, 0, 0);
            o1 = __builtin_amdgcn_mfma_f32_16x16x32_f16(pa[k4], b1, o1, 0, 0, 0);
        }
        #pragma unroll
        for (int r = 0; r < 4; ++r) {
            size_t rw = (size_t)(row0 + w * 16 + 4 * lk + r) * DQ + c * 32;
            __builtin_nontemporal_store(o0[r], &out[rw + lr]);       // ONLY change vs r6
            __builtin_nontemporal_store(o1[r], &out[rw + 16 + lr]);  // ONLY change vs r6
        }
        if (c == 0)       { WAITV(9); }         // V(1) done: newer = V(2)+8 stores
        else if (c <= 29) { WAITV(17); }        // V(c+1) done: newer = 8+1+8
        else if (c == 30) { WAITV(16); }        // no V(32) stage: newer = 8+8
        if (c < 31) __builtin_amdgcn_s_barrier();
        if (++vc == 3) vc = 0;
    }
}

extern "C" void kernel_launch(void* const* d_in, const int* in_sizes, int n_in,
                              void* d_out, int out_size, void* d_ws, size_t ws_size,
                              hipStream_t stream) {
    const float* q  = (const float*)d_in[0];
    const float* cx = (const float*)d_in[1];
    const float* mk = (const float*)d_in[2];
    const float* mv = (const float*)d_in[3];
    const float* mc = (const float*)d_in[4];
    const float* ts = (const float*)d_in[5];
    float* out = (float*)d_out;

    _Float16* wsp = (_Float16*)d_ws;
    _Float16* KH = wsp;                        // [112][1056]
    _Float16* VT = wsp + KE;                   // [1024][128]

    const int B = in_sizes[0] / DQ;            // 131072

    build_k<<<dim3(17, 112), dim3(64), 0, stream>>>(mk, mc, KH);
    build_vt<<<dim3(512), dim3(256), 0, stream>>>(mv, VT);
    epmem_pipe<<<dim3(B / 128), dim3(512), 0, stream>>>(q, cx, ts, KH, VT, out);
}